// Round 9
// baseline (449.675 us; speedup 1.0000x reference)
//
#include <hip/hip_runtime.h>

#define HW 512
#define NPIX (HW*HW)
#define NSAMP 64
#define KSEL 2621
#define NF 3
#define NQ (NF*NSAMP)
#define CAP 16384
#define CPAD 32     // count padding (uints) -> 128B per counter, no false sharing

#define HALO 3      // max filter halo
#define LSTR 520    // LDS row stride in floats (16B-aligned, bank-friendly)
#define ROWS 16     // strip rows
#define TR (ROWS + 2*HALO)   // 22
#define NV4 (TR*128)         // float4 count per staged strip = 2816

// Sample bracket ranks (of 32768 samples). Exactness never depends on the
// bracket: invalid/overflow cases take the full-plane fallback in sel_final.
#define RANK_HI 8
#define RANK_LO 980

// Weight LDS offsets in the combined array
#define W3OFF 0
#define W5OFF 9
#define W7OFF 34
#define WTOT 83

// ===========================================================================
// Row-streaming conv (round-5 lesson: small live set, no spills).
// ===========================================================================
template<int K, int R>
__device__ __forceinline__ void conv_rows_f64(
    const float (*xt)[LSTR], const double* __restrict__ wsm,
    int tx, double* __restrict__ acc)
{
  constexpr int ROFF = HALO - K/2;
  constexpr int COFF = 4 - K/2;
  #pragma unroll
  for (int y = 0; y < R + K - 1; ++y) {
    double v[K];
    #pragma unroll
    for (int j = 0; j < K; ++j)
      v[j] = (double)xt[y + ROFF][tx + j + COFF];
    #pragma unroll
    for (int i = 0; i < K; ++i) {
      const int r = y - i;                 // compile-time after unroll
      if (r >= 0 && r < R) {
        #pragma unroll
        for (int j = 0; j < K; ++j)
          acc[r] = fma(v[j], wsm[i*K + j], acc[r]);
      }
    }
  }
}

template<int K, int R>
__device__ __forceinline__ void conv_rows_f32(
    const float (*xt)[LSTR], const float* __restrict__ wsm,
    int tx, float* __restrict__ acc)
{
  constexpr int ROFF = HALO - K/2;
  constexpr int COFF = 4 - K/2;
  #pragma unroll
  for (int y = 0; y < R + K - 1; ++y) {
    float v[K];
    #pragma unroll
    for (int j = 0; j < K; ++j)
      v[j] = xt[y + ROFF][tx + j + COFF];
    #pragma unroll
    for (int i = 0; i < K; ++i) {
      const int r = y - i;
      if (r >= 0 && r < R) {
        #pragma unroll
        for (int j = 0; j < K; ++j)
          acc[r] = fmaf(v[j], wsm[i*K + j], acc[r]);
      }
    }
  }
}

// Descending scans of LDS hist (coarse-256 + fine).
__device__ __forceinline__ void scan2048_desc(
    const unsigned* lh, unsigned* part, int t, unsigned kr,
    unsigned* out_bin, unsigned* out_krem)
{
  unsigned sum = 0;
  #pragma unroll
  for (int i = 0; i < 8; ++i) sum += lh[t*8 + i];
  part[t] = sum;
  __syncthreads();
  if (t == 0) {
    unsigned cum = 0; int sc = 0;
    for (int c = 255; c >= 0; --c) {
      if (cum + part[c] >= kr) { sc = c; break; }
      cum += part[c];
    }
    unsigned cum2 = cum; int sb = sc*8;
    for (int b = sc*8 + 7; b >= sc*8; --b) {
      if (cum2 + lh[b] >= kr) { sb = b; break; }
      cum2 += lh[b];
    }
    *out_bin = (unsigned)sb; *out_krem = kr - cum2;
  }
  __syncthreads();
}

__device__ __forceinline__ void scan512_desc(
    const unsigned* lh, unsigned* part, int t, unsigned kr,
    unsigned* out_bin)
{
  part[t] = lh[2*t] + lh[2*t + 1];
  __syncthreads();
  if (t == 0) {
    unsigned cum = 0; int sc = 0;
    for (int c = 255; c >= 0; --c) {
      if (cum + part[c] >= kr) { sc = c; break; }
      cum += part[c];
    }
    unsigned cum2 = cum; int sb = 2*sc;
    for (int b = 2*sc + 1; b >= 2*sc; --b) {
      if (cum2 + lh[b] >= kr) { sb = b; break; }
      cum2 += lh[b];
    }
    *out_bin = (unsigned)sb;
  }
  __syncthreads();
}

// ===========================================================================
// Forward: pure fp64 conv, NO histogram, NO inter-filter barriers (all three
// weight sets preloaded; xt read-only after the single staging sync; stores
// of filter f overlap conv of filter f+1).
// ===========================================================================
__global__ __launch_bounds__(512, 2) void fwd_all(
    const float* __restrict__ x,
    const float* __restrict__ w3, const float* __restrict__ w5,
    const float* __restrict__ w7,
    float* __restrict__ sims)
{
  __shared__ float xt[TR][LSTR];
  __shared__ double wsm[WTOT];

  const int tid = threadIdx.x;
  const int s  = blockIdx.y;
  const int by = blockIdx.x * ROWS;
  const float* __restrict__ xs = x + (size_t)s*NPIX;

  // all three filters, once
  if (tid < WTOT) {
    double wv;
    if (tid < W5OFF)      wv = (double)w3[tid];
    else if (tid < W7OFF) wv = (double)w5[tid - W5OFF];
    else                  wv = (double)w7[tid - W7OFF];
    wsm[tid] = wv;
  }
  // zero x-halo pads: cols 0..3 and 516..519
  if (tid < TR*8) {
    const int r = tid >> 3, c = tid & 7;
    xt[r][(c < 4) ? c : 512 + c] = 0.0f;
  }
  // stage TR rows x 128 float4 (data at float offset 4 -> 16B aligned)
  for (int idx = tid; idx < NV4; idx += 512) {
    const int r = idx >> 7, c4 = idx & 127;
    const int gy = by + r - HALO;
    float4 v = make_float4(0.f, 0.f, 0.f, 0.f);
    if (gy >= 0 && gy < HW)
      v = ((const float4*)(xs + (size_t)gy*HW))[c4];
    *(float4*)&xt[r][4 + 4*c4] = v;
  }
  __syncthreads();

  const int tx = tid;
  const size_t obase = (size_t)s*NPIX + (size_t)by*HW + tx;

  {
    double acc[ROWS];
    #pragma unroll
    for (int r = 0; r < ROWS; ++r) acc[r] = 0.0;
    conv_rows_f64<3, ROWS>(xt, wsm + W3OFF, tx, acc);
    float* __restrict__ so = sims + 0*(size_t)NSAMP*NPIX + obase;
    #pragma unroll
    for (int r = 0; r < ROWS; ++r) so[(size_t)r*HW] = (float)acc[r];
  }
  {
    double acc[ROWS];
    #pragma unroll
    for (int r = 0; r < ROWS; ++r) acc[r] = 0.0;
    conv_rows_f64<5, ROWS>(xt, wsm + W5OFF, tx, acc);
    float* __restrict__ so = sims + 1*(size_t)NSAMP*NPIX + obase;
    #pragma unroll
    for (int r = 0; r < ROWS; ++r) so[(size_t)r*HW] = (float)acc[r];
  }
  {
    double acc[ROWS];
    #pragma unroll
    for (int r = 0; r < ROWS; ++r) acc[r] = 0.0;
    conv_rows_f64<7, ROWS>(xt, wsm + W7OFF, tx, acc);
    float* __restrict__ so = sims + 2*(size_t)NSAMP*NPIX + obase;
    #pragma unroll
    for (int r = 0; r < ROWS; ++r) so[(size_t)r*HW] = (float)acc[r];
  }
}

// ===========================================================================
// Sample: 32768 coalesced samples per q, coarse hist of bits[30:20], bracket
// thresholds at sample ranks RANK_HI / RANK_LO.
// ===========================================================================
__global__ __launch_bounds__(256) void sample_all(
    const float* __restrict__ sims, unsigned* __restrict__ tlo,
    unsigned* __restrict__ thi)
{
  __shared__ unsigned lh[2048];
  __shared__ unsigned part[256];
  __shared__ unsigned sbin, skrem;
  const int q = blockIdx.x, t = threadIdx.x;
  for (int i = t; i < 2048; i += 256) lh[i] = 0;
  __syncthreads();

  const float* __restrict__ sq = sims + (size_t)q*NPIX;
  for (int rep = 0; rep < 128; ++rep) {
    const unsigned b = __float_as_uint(sq[rep*2048 + t]) & 0x7fffffffu;
    atomicAdd(&lh[b >> 20], 1u);
  }
  __syncthreads();

  scan2048_desc(lh, part, t, RANK_HI, &sbin, &skrem);
  const unsigned bhi = sbin;
  scan2048_desc(lh, part, t, RANK_LO, &sbin, &skrem);
  const unsigned blo = sbin;
  if (t == 0) {
    unsigned Th = (bhi == blo) ? ((bhi + 1u) << 20) : (bhi << 20);
    tlo[q] = blo << 20;
    thi[q] = Th;
  }
}

// ===========================================================================
// Count + compact: register count of bits >= T_hi (shfl-reduced, one global
// atomic per block); candidates in [T_lo, T_hi) via LDS aggregation + one
// padded global atomic (round-3 lesson: no per-element device atomics).
// ===========================================================================
__global__ __launch_bounds__(256) void count_compact(
    const float* __restrict__ sims, const unsigned* __restrict__ tlo,
    const unsigned* __restrict__ thi, unsigned* __restrict__ cntA,
    unsigned* __restrict__ cntC, unsigned* __restrict__ cand)
{
  __shared__ unsigned sb[4096];
  __shared__ unsigned scnt, sbase, sA;
  const int tid = threadIdx.x;
  const int q = blockIdx.y;
  if (tid == 0) { scnt = 0; sA = 0; }
  __syncthreads();

  const unsigned Tl = tlo[q], Th = thi[q];
  const float4* __restrict__ p =
      (const float4*)(sims + (size_t)q*NPIX) + (size_t)blockIdx.x*1024;
  unsigned ca = 0;
  #pragma unroll
  for (int k = 0; k < 4; ++k) {
    const float4 v = p[k*256 + tid];
    const float f4[4] = {v.x, v.y, v.z, v.w};
    #pragma unroll
    for (int e = 0; e < 4; ++e) {
      const unsigned bits = __float_as_uint(f4[e]) & 0x7fffffffu;
      ca += (bits >= Th);
      if (bits >= Tl && bits < Th) {
        const unsigned pos = atomicAdd(&scnt, 1u);
        if (pos < 4096) sb[pos] = bits;
      }
    }
  }
  #pragma unroll
  for (int o = 32; o > 0; o >>= 1) ca += __shfl_down(ca, o);
  if ((tid & 63) == 0 && ca) atomicAdd(&sA, ca);
  __syncthreads();

  const unsigned nb = scnt;
  if (tid == 0) {
    if (sA) atomicAdd(&cntA[(size_t)q*CPAD], sA);
    sbase = nb ? atomicAdd(&cntC[(size_t)q*CPAD], nb) : 0u;
    if (nb > 4096) atomicAdd(&cntC[(size_t)q*CPAD], (unsigned)(CAP + 1)); // poison -> fallback
  }
  __syncthreads();
  const unsigned base = sbase;
  const unsigned nstore = (nb < 4096u) ? nb : 4096u;
  for (unsigned i = tid; i < nstore; i += 256) {
    const unsigned pos = base + i;
    if (pos < CAP) cand[(size_t)q*CAP + pos] = sb[i];
  }
}

// ===========================================================================
// Exact selection: kth-largest = (KSEL-nA)th largest in C. 3-level radix on
// the compact list; full-plane fallback if bracket invalid/overflow.
// ===========================================================================
__global__ __launch_bounds__(256) void sel_final(
    const unsigned* __restrict__ cntA, const unsigned* __restrict__ cntC,
    const unsigned* __restrict__ cand, const float* __restrict__ sims,
    unsigned* __restrict__ thb)
{
  __shared__ unsigned lh[2048];
  __shared__ unsigned part[256];
  __shared__ unsigned sbin, skrem;
  const int q = blockIdx.x, t = threadIdx.x;

  const unsigned nA = cntA[(size_t)q*CPAD];
  const unsigned nC = cntC[(size_t)q*CPAD];
  const unsigned* __restrict__ cq = cand + (size_t)q*CAP;
  const float*    __restrict__ sq = sims + (size_t)q*NPIX;
  const bool ok = (nA < KSEL) && (nA + nC >= KSEL) && (nC <= CAP);
  const unsigned kr0 = ok ? (KSEL - nA) : (unsigned)KSEL;

  for (int i = t; i < 2048; i += 256) lh[i] = 0;
  __syncthreads();
  if (ok) {
    for (unsigned i = t; i < nC; i += 256) atomicAdd(&lh[cq[i] >> 20], 1u);
  } else {
    for (int i = t; i < NPIX; i += 256) {
      const unsigned b = __float_as_uint(sq[i]) & 0x7fffffffu;
      atomicAdd(&lh[b >> 20], 1u);
    }
  }
  __syncthreads();
  scan2048_desc(lh, part, t, kr0, &sbin, &skrem);
  const unsigned pfx1 = sbin << 20;
  const unsigned kr1  = skrem;

  for (int i = t; i < 2048; i += 256) lh[i] = 0;
  __syncthreads();
  if (ok) {
    for (unsigned i = t; i < nC; i += 256) {
      const unsigned b = cq[i];
      if ((b >> 20) == (pfx1 >> 20)) atomicAdd(&lh[(b >> 9) & 0x7ffu], 1u);
    }
  } else {
    for (int i = t; i < NPIX; i += 256) {
      const unsigned b = __float_as_uint(sq[i]) & 0x7fffffffu;
      if ((b >> 20) == (pfx1 >> 20)) atomicAdd(&lh[(b >> 9) & 0x7ffu], 1u);
    }
  }
  __syncthreads();
  scan2048_desc(lh, part, t, kr1, &sbin, &skrem);
  const unsigned pfx2 = pfx1 | (sbin << 9);
  const unsigned kr2  = skrem;

  for (int i = t; i < 512; i += 256) lh[i] = 0;
  __syncthreads();
  if (ok) {
    for (unsigned i = t; i < nC; i += 256) {
      const unsigned b = cq[i];
      if ((b >> 9) == (pfx2 >> 9)) atomicAdd(&lh[b & 0x1ffu], 1u);
    }
  } else {
    for (int i = t; i < NPIX; i += 256) {
      const unsigned b = __float_as_uint(sq[i]) & 0x7fffffffu;
      if ((b >> 9) == (pfx2 >> 9)) atomicAdd(&lh[b & 0x1ffu], 1u);
    }
  }
  __syncthreads();
  scan512_desc(lh, part, t, kr2, &sbin);
  if (t == 0) thb[q] = pfx2 | sbin;
}

// ===========================================================================
// Backward with async-STAGE split (G15/T14): issue filter-(f+1) global loads
// into registers BEFORE conv f (HBM latency hides under conv VALU), then
// threshold + ds_write after the post-conv barrier.
// ===========================================================================
__device__ __forceinline__ void bwd_issue(
    const float* __restrict__ ss, int by, int tid, float4* pre)
{
  #pragma unroll
  for (int i = 0; i < 6; ++i) {
    const int idx = tid + i*512;
    float4 v = make_float4(0.f, 0.f, 0.f, 0.f);
    if (idx < NV4) {
      const int gy = by + (idx >> 7) - HALO;
      if (gy >= 0 && gy < HW)
        v = ((const float4*)(ss + (size_t)gy*HW))[idx & 127];
    }
    pre[i] = v;
  }
}

__device__ __forceinline__ void bwd_commit(
    float (*xt)[LSTR], int tid, unsigned th, const float4* pre)
{
  #pragma unroll
  for (int i = 0; i < 6; ++i) {
    const int idx = tid + i*512;
    if (idx < NV4) {
      float4 v = pre[i];
      if ((__float_as_uint(v.x) & 0x7fffffffu) < th) v.x = 0.0f;
      if ((__float_as_uint(v.y) & 0x7fffffffu) < th) v.y = 0.0f;
      if ((__float_as_uint(v.z) & 0x7fffffffu) < th) v.z = 0.0f;
      if ((__float_as_uint(v.w) & 0x7fffffffu) < th) v.w = 0.0f;
      *(float4*)&xt[idx >> 7][4 + 4*(idx & 127)] = v;
    }
  }
}

__global__ __launch_bounds__(512, 2) void bwd_all(
    const float* __restrict__ sims,
    const float* __restrict__ w3, const float* __restrict__ w5,
    const float* __restrict__ w7,
    const unsigned* __restrict__ thb, float* __restrict__ out)
{
  __shared__ float xt[TR][LSTR];
  __shared__ float wsm[WTOT];

  const int tid = threadIdx.x;
  const int s  = blockIdx.y;
  const int by = blockIdx.x * ROWS;
  const int tx = tid;

  if (tid < WTOT) {
    float wv;
    if (tid < W5OFF)      wv = w3[tid];
    else if (tid < W7OFF) wv = w5[tid - W5OFF];
    else                  wv = w7[tid - W7OFF];
    wsm[tid] = wv;
  }
  if (tid < TR*8) {
    const int r = tid >> 3, c = tid & 7;
    xt[r][(c < 4) ? c : 512 + c] = 0.0f;
  }

  const float* __restrict__ ss0 = sims + ((size_t)0*NSAMP + s)*NPIX;
  const float* __restrict__ ss1 = sims + ((size_t)1*NSAMP + s)*NPIX;
  const float* __restrict__ ss2 = sims + ((size_t)2*NSAMP + s)*NPIX;
  const unsigned th0 = thb[0*NSAMP + s];
  const unsigned th1 = thb[1*NSAMP + s];
  const unsigned th2 = thb[2*NSAMP + s];

  float acc[ROWS];
  #pragma unroll
  for (int r = 0; r < ROWS; ++r) acc[r] = 0.0f;

  float4 pre[6];

  // stage f0
  bwd_issue(ss0, by, tid, pre);
  bwd_commit(xt, tid, th0, pre);
  __syncthreads();

  // f0: prefetch f1 under conv3
  bwd_issue(ss1, by, tid, pre);
  conv_rows_f32<3, ROWS>(xt, wsm + W3OFF, tx, acc);
  __syncthreads();
  bwd_commit(xt, tid, th1, pre);
  __syncthreads();

  // f1: prefetch f2 under conv5
  bwd_issue(ss2, by, tid, pre);
  conv_rows_f32<5, ROWS>(xt, wsm + W5OFF, tx, acc);
  __syncthreads();
  bwd_commit(xt, tid, th2, pre);
  __syncthreads();

  // f2
  conv_rows_f32<7, ROWS>(xt, wsm + W7OFF, tx, acc);

  float* __restrict__ oo = out + (size_t)s*NPIX + (size_t)by*HW + tx;
  #pragma unroll
  for (int r = 0; r < ROWS; ++r)
    oo[(size_t)r*HW] = acc[r];
}

// ===========================================================================
extern "C" void kernel_launch(void* const* d_in, const int* in_sizes, int n_in,
                              void* d_out, int out_size, void* d_ws, size_t ws_size,
                              hipStream_t stream)
{
  const float* x  = (const float*)d_in[0];
  const float* w3 = (const float*)d_in[1];
  const float* w5 = (const float*)d_in[2];
  const float* w7 = (const float*)d_in[3];
  float* out = (float*)d_out;
  char* ws = (char*)d_ws;

  const size_t SIMS_B = (size_t)NF*NSAMP*NPIX*sizeof(float);   // 192 MB
  const size_t CNT_B  = (size_t)NQ*CPAD*sizeof(unsigned);      // 24 KB each

  float*    sims = (float*)ws;
  unsigned* cntA = (unsigned*)(ws + SIMS_B);
  unsigned* cntC = cntA + (size_t)NQ*CPAD;
  unsigned* tlo  = cntC + (size_t)NQ*CPAD;
  unsigned* thi  = tlo + NQ;
  unsigned* thb  = thi + NQ;
  unsigned* cand = thb + NQ + NQ;      // spare NQ gap

  hipMemsetAsync(cntA, 0, 2*CNT_B, stream);   // cntA + cntC contiguous

  dim3 b512(512, 1, 1);
  dim3 sg(HW/ROWS, NSAMP, 1);          // 32 x 64 strips
  fwd_all<<<sg, b512, 0, stream>>>(x, w3, w5, w7, sims);
  sample_all<<<NQ, 256, 0, stream>>>(sims, tlo, thi);
  dim3 rg(NPIX/4096, NQ, 1);
  count_compact<<<rg, dim3(256,1,1), 0, stream>>>(sims, tlo, thi, cntA, cntC, cand);
  sel_final<<<NQ, 256, 0, stream>>>(cntA, cntC, cand, sims, thb);
  bwd_all<<<sg, b512, 0, stream>>>(sims, w3, w5, w7, thb, out);
}

// Round 10
// 432.818 us; speedup vs baseline: 1.0389x; 1.0389x over previous
//
#include <hip/hip_runtime.h>

#define HW 512
#define NPIX (HW*HW)
#define NSAMP 64
#define KSEL 2621
#define NF 3
#define NQ (NF*NSAMP)
#define CAP 16384
#define CPAD 32     // count padding (uints) -> 128B per counter, no false sharing
#define SBCAP 2048  // per-block candidate buffer (E~292, ~14 sigma margin)

#define HALO 3
#define LSTR 520    // LDS row stride in floats (16B-aligned, bank-friendly)
#define ROWS 16
#define TR (ROWS + 2*HALO)   // 22
#define NV4 (TR*128)         // staged float4 per strip = 2816

// Analytic bracket: sim ~ N(0, ||w||^2) exactly (x iid normal). Exactness
// never depends on these; violations poison -> full-plane fallback.
#define Z_HI 3.0
#define Z_LO 2.1

// Weight LDS offsets
#define W3OFF 0
#define W5OFF 9
#define W7OFF 34
#define WTOT 83

// ===========================================================================
// Row-streaming conv (round-5 lesson: small live set, no spills).
// ===========================================================================
template<int K, int R>
__device__ __forceinline__ void conv_rows_f64(
    const float (*xt)[LSTR], const double* __restrict__ wsm,
    int tx, double* __restrict__ acc)
{
  constexpr int ROFF = HALO - K/2;
  constexpr int COFF = 4 - K/2;
  #pragma unroll
  for (int y = 0; y < R + K - 1; ++y) {
    double v[K];
    #pragma unroll
    for (int j = 0; j < K; ++j)
      v[j] = (double)xt[y + ROFF][tx + j + COFF];
    #pragma unroll
    for (int i = 0; i < K; ++i) {
      const int r = y - i;                 // compile-time after unroll
      if (r >= 0 && r < R) {
        #pragma unroll
        for (int j = 0; j < K; ++j)
          acc[r] = fma(v[j], wsm[i*K + j], acc[r]);
      }
    }
  }
}

template<int K, int R>
__device__ __forceinline__ void conv_rows_f32(
    const float (*xt)[LSTR], const float* __restrict__ wsm,
    int tx, float* __restrict__ acc)
{
  constexpr int ROFF = HALO - K/2;
  constexpr int COFF = 4 - K/2;
  #pragma unroll
  for (int y = 0; y < R + K - 1; ++y) {
    float v[K];
    #pragma unroll
    for (int j = 0; j < K; ++j)
      v[j] = xt[y + ROFF][tx + j + COFF];
    #pragma unroll
    for (int i = 0; i < K; ++i) {
      const int r = y - i;
      if (r >= 0 && r < R) {
        #pragma unroll
        for (int j = 0; j < K; ++j)
          acc[r] = fmaf(v[j], wsm[i*K + j], acc[r]);
      }
    }
  }
}

// Descending scans of LDS hist (coarse-256 + fine).
__device__ __forceinline__ void scan2048_desc(
    const unsigned* lh, unsigned* part, int t, unsigned kr,
    unsigned* out_bin, unsigned* out_krem)
{
  unsigned sum = 0;
  #pragma unroll
  for (int i = 0; i < 8; ++i) sum += lh[t*8 + i];
  part[t] = sum;
  __syncthreads();
  if (t == 0) {
    unsigned cum = 0; int sc = 0;
    for (int c = 255; c >= 0; --c) {
      if (cum + part[c] >= kr) { sc = c; break; }
      cum += part[c];
    }
    unsigned cum2 = cum; int sb = sc*8;
    for (int b = sc*8 + 7; b >= sc*8; --b) {
      if (cum2 + lh[b] >= kr) { sb = b; break; }
      cum2 += lh[b];
    }
    *out_bin = (unsigned)sb; *out_krem = kr - cum2;
  }
  __syncthreads();
}

__device__ __forceinline__ void scan512_desc(
    const unsigned* lh, unsigned* part, int t, unsigned kr,
    unsigned* out_bin)
{
  part[t] = lh[2*t] + lh[2*t + 1];
  __syncthreads();
  if (t == 0) {
    unsigned cum = 0; int sc = 0;
    for (int c = 255; c >= 0; --c) {
      if (cum + part[c] >= kr) { sc = c; break; }
      cum += part[c];
    }
    unsigned cum2 = cum; int sb = 2*sc;
    for (int b = 2*sc + 1; b >= 2*sc; --b) {
      if (cum2 + lh[b] >= kr) { sb = b; break; }
      cum2 += lh[b];
    }
    *out_bin = (unsigned)sb;
  }
  __syncthreads();
}

// ===========================================================================
// winit: analytic bracket thresholds from ||w||_2 per filter.
// ===========================================================================
__global__ void winit(const float* __restrict__ w3, const float* __restrict__ w5,
                      const float* __restrict__ w7, unsigned* __restrict__ tlo,
                      unsigned* __restrict__ thi)
{
  const int t = threadIdx.x;
  if (t < 3) {
    const float* w = (t == 0) ? w3 : (t == 1) ? w5 : w7;
    const int n = (t == 0) ? 9 : (t == 1) ? 25 : 49;
    double s2 = 0.0;
    for (int i = 0; i < n; ++i) s2 = fma((double)w[i], (double)w[i], s2);
    const double sig = sqrt(s2);
    tlo[t] = __float_as_uint((float)(Z_LO * sig));
    thi[t] = __float_as_uint((float)(Z_HI * sig));
  }
}

// ===========================================================================
// Forward: fp64 conv (exact selection), per-filter barriers (round-9 lesson:
// removing them merged the three convs' live ranges -> 128-VGPR spill,
// 539MB phantom writes). Fused bracket count+compact in the epilogue
// (round-3 lesson: LDS aggregation + one padded global atomic per block).
// ===========================================================================
__global__ __launch_bounds__(512, 2) void fwd_all(
    const float* __restrict__ x,
    const float* __restrict__ w3, const float* __restrict__ w5,
    const float* __restrict__ w7,
    float* __restrict__ sims,
    const unsigned* __restrict__ tlo, const unsigned* __restrict__ thi,
    unsigned* __restrict__ cntA, unsigned* __restrict__ cntC,
    unsigned* __restrict__ cand)
{
  __shared__ float xt[TR][LSTR];
  __shared__ double wsm[WTOT];
  __shared__ unsigned sb[SBCAP];
  __shared__ unsigned scnt, sA, sbase;

  const int tid = threadIdx.x;
  const int s  = blockIdx.y;
  const int by = blockIdx.x * ROWS;
  const float* __restrict__ xs = x + (size_t)s*NPIX;

  if (tid < WTOT) {
    double wv;
    if (tid < W5OFF)      wv = (double)w3[tid];
    else if (tid < W7OFF) wv = (double)w5[tid - W5OFF];
    else                  wv = (double)w7[tid - W7OFF];
    wsm[tid] = wv;
  }
  if (tid == 0) { scnt = 0; sA = 0; }
  if (tid < TR*8) {
    const int r = tid >> 3, c = tid & 7;
    xt[r][(c < 4) ? c : 512 + c] = 0.0f;
  }
  for (int idx = tid; idx < NV4; idx += 512) {
    const int r = idx >> 7, c4 = idx & 127;
    const int gy = by + r - HALO;
    float4 v = make_float4(0.f, 0.f, 0.f, 0.f);
    if (gy >= 0 && gy < HW)
      v = ((const float4*)(xs + (size_t)gy*HW))[c4];
    *(float4*)&xt[r][4 + 4*c4] = v;
  }
  __syncthreads();

  const int tx = tid;
  const size_t obase = (size_t)s*NPIX + (size_t)by*HW + tx;

  #pragma unroll
  for (int f = 0; f < NF; ++f) {
    const unsigned Tl = tlo[f], Th = thi[f];
    const int q = f*NSAMP + s;

    double acc[ROWS];
    #pragma unroll
    for (int r = 0; r < ROWS; ++r) acc[r] = 0.0;
    if (f == 0)      conv_rows_f64<3, ROWS>(xt, wsm + W3OFF, tx, acc);
    else if (f == 1) conv_rows_f64<5, ROWS>(xt, wsm + W5OFF, tx, acc);
    else             conv_rows_f64<7, ROWS>(xt, wsm + W7OFF, tx, acc);

    float* __restrict__ so = sims + (size_t)f*NSAMP*NPIX + obase;
    unsigned ca = 0;
    #pragma unroll
    for (int r = 0; r < ROWS; ++r) {
      const float sv = (float)acc[r];
      so[(size_t)r*HW] = sv;
      const unsigned bits = __float_as_uint(sv) & 0x7fffffffu;
      ca += (bits >= Th);
      if (bits >= Tl && bits < Th) {
        const unsigned pos = atomicAdd(&scnt, 1u);
        if (pos < SBCAP) sb[pos] = bits;
      }
    }
    #pragma unroll
    for (int o = 32; o > 0; o >>= 1) ca += __shfl_down(ca, o);
    if ((tid & 63) == 0 && ca) atomicAdd(&sA, ca);
    __syncthreads();

    const unsigned nb = scnt;
    if (tid == 0) {
      if (sA) atomicAdd(&cntA[(size_t)q*CPAD], sA);
      sbase = nb ? atomicAdd(&cntC[(size_t)q*CPAD], nb) : 0u;
      if (nb > SBCAP) atomicAdd(&cntC[(size_t)q*CPAD], (unsigned)(CAP + 1)); // poison -> fallback
    }
    __syncthreads();
    const unsigned base = sbase;
    const unsigned nstore = (nb < (unsigned)SBCAP) ? nb : (unsigned)SBCAP;
    for (unsigned i = tid; i < nstore; i += 512) {
      const unsigned pos = base + i;
      if (pos < CAP) cand[(size_t)q*CAP + pos] = sb[i];
    }
    if (f < NF - 1) {
      __syncthreads();
      if (tid == 0) { scnt = 0; sA = 0; }
      __syncthreads();
    }
  }
}

// ===========================================================================
// Exact selection: kth-largest = (KSEL-nA)th largest among candidates.
// 3-level radix on the compact list; full-plane fallback if bracket
// invalid/overflowed (poisoned cntC).
// ===========================================================================
__global__ __launch_bounds__(256) void sel_final(
    const unsigned* __restrict__ cntA, const unsigned* __restrict__ cntC,
    const unsigned* __restrict__ cand, const float* __restrict__ sims,
    unsigned* __restrict__ thb)
{
  __shared__ unsigned lh[2048];
  __shared__ unsigned part[256];
  __shared__ unsigned sbin, skrem;
  const int q = blockIdx.x, t = threadIdx.x;

  const unsigned nA = cntA[(size_t)q*CPAD];
  const unsigned nC = cntC[(size_t)q*CPAD];
  const unsigned* __restrict__ cq = cand + (size_t)q*CAP;
  const float*    __restrict__ sq = sims + (size_t)q*NPIX;
  const bool ok = (nA < KSEL) && (nA + nC >= KSEL) && (nC <= CAP);
  const unsigned kr0 = ok ? (KSEL - nA) : (unsigned)KSEL;

  for (int i = t; i < 2048; i += 256) lh[i] = 0;
  __syncthreads();
  if (ok) {
    for (unsigned i = t; i < nC; i += 256) atomicAdd(&lh[cq[i] >> 20], 1u);
  } else {
    for (int i = t; i < NPIX; i += 256) {
      const unsigned b = __float_as_uint(sq[i]) & 0x7fffffffu;
      atomicAdd(&lh[b >> 20], 1u);
    }
  }
  __syncthreads();
  scan2048_desc(lh, part, t, kr0, &sbin, &skrem);
  const unsigned pfx1 = sbin << 20;
  const unsigned kr1  = skrem;

  for (int i = t; i < 2048; i += 256) lh[i] = 0;
  __syncthreads();
  if (ok) {
    for (unsigned i = t; i < nC; i += 256) {
      const unsigned b = cq[i];
      if ((b >> 20) == (pfx1 >> 20)) atomicAdd(&lh[(b >> 9) & 0x7ffu], 1u);
    }
  } else {
    for (int i = t; i < NPIX; i += 256) {
      const unsigned b = __float_as_uint(sq[i]) & 0x7fffffffu;
      if ((b >> 20) == (pfx1 >> 20)) atomicAdd(&lh[(b >> 9) & 0x7ffu], 1u);
    }
  }
  __syncthreads();
  scan2048_desc(lh, part, t, kr1, &sbin, &skrem);
  const unsigned pfx2 = pfx1 | (sbin << 9);
  const unsigned kr2  = skrem;

  for (int i = t; i < 512; i += 256) lh[i] = 0;
  __syncthreads();
  if (ok) {
    for (unsigned i = t; i < nC; i += 256) {
      const unsigned b = cq[i];
      if ((b >> 9) == (pfx2 >> 9)) atomicAdd(&lh[b & 0x1ffu], 1u);
    }
  } else {
    for (int i = t; i < NPIX; i += 256) {
      const unsigned b = __float_as_uint(sq[i]) & 0x7fffffffu;
      if ((b >> 9) == (pfx2 >> 9)) atomicAdd(&lh[b & 0x1ffu], 1u);
    }
  }
  __syncthreads();
  scan512_desc(lh, part, t, kr2, &sbin);
  if (t == 0) thb[q] = pfx2 | sbin;
}

// ===========================================================================
// Backward with async-STAGE split: issue filter-(f+1) loads to registers
// before conv f, threshold + LDS-write after the post-conv barrier.
// ===========================================================================
__device__ __forceinline__ void bwd_issue(
    const float* __restrict__ ss, int by, int tid, float4* pre)
{
  #pragma unroll
  for (int i = 0; i < 6; ++i) {
    const int idx = tid + i*512;
    float4 v = make_float4(0.f, 0.f, 0.f, 0.f);
    if (idx < NV4) {
      const int gy = by + (idx >> 7) - HALO;
      if (gy >= 0 && gy < HW)
        v = ((const float4*)(ss + (size_t)gy*HW))[idx & 127];
    }
    pre[i] = v;
  }
}

__device__ __forceinline__ void bwd_commit(
    float (*xt)[LSTR], int tid, unsigned th, const float4* pre)
{
  #pragma unroll
  for (int i = 0; i < 6; ++i) {
    const int idx = tid + i*512;
    if (idx < NV4) {
      float4 v = pre[i];
      if ((__float_as_uint(v.x) & 0x7fffffffu) < th) v.x = 0.0f;
      if ((__float_as_uint(v.y) & 0x7fffffffu) < th) v.y = 0.0f;
      if ((__float_as_uint(v.z) & 0x7fffffffu) < th) v.z = 0.0f;
      if ((__float_as_uint(v.w) & 0x7fffffffu) < th) v.w = 0.0f;
      *(float4*)&xt[idx >> 7][4 + 4*(idx & 127)] = v;
    }
  }
}

__global__ __launch_bounds__(512, 2) void bwd_all(
    const float* __restrict__ sims,
    const float* __restrict__ w3, const float* __restrict__ w5,
    const float* __restrict__ w7,
    const unsigned* __restrict__ thb, float* __restrict__ out)
{
  __shared__ float xt[TR][LSTR];
  __shared__ float wsm[WTOT];

  const int tid = threadIdx.x;
  const int s  = blockIdx.y;
  const int by = blockIdx.x * ROWS;
  const int tx = tid;

  if (tid < WTOT) {
    float wv;
    if (tid < W5OFF)      wv = w3[tid];
    else if (tid < W7OFF) wv = w5[tid - W5OFF];
    else                  wv = w7[tid - W7OFF];
    wsm[tid] = wv;
  }
  if (tid < TR*8) {
    const int r = tid >> 3, c = tid & 7;
    xt[r][(c < 4) ? c : 512 + c] = 0.0f;
  }

  const float* __restrict__ ss0 = sims + ((size_t)0*NSAMP + s)*NPIX;
  const float* __restrict__ ss1 = sims + ((size_t)1*NSAMP + s)*NPIX;
  const float* __restrict__ ss2 = sims + ((size_t)2*NSAMP + s)*NPIX;
  const unsigned th0 = thb[0*NSAMP + s];
  const unsigned th1 = thb[1*NSAMP + s];
  const unsigned th2 = thb[2*NSAMP + s];

  float acc[ROWS];
  #pragma unroll
  for (int r = 0; r < ROWS; ++r) acc[r] = 0.0f;

  float4 pre[6];

  bwd_issue(ss0, by, tid, pre);
  bwd_commit(xt, tid, th0, pre);
  __syncthreads();

  bwd_issue(ss1, by, tid, pre);
  conv_rows_f32<3, ROWS>(xt, wsm + W3OFF, tx, acc);
  __syncthreads();
  bwd_commit(xt, tid, th1, pre);
  __syncthreads();

  bwd_issue(ss2, by, tid, pre);
  conv_rows_f32<5, ROWS>(xt, wsm + W5OFF, tx, acc);
  __syncthreads();
  bwd_commit(xt, tid, th2, pre);
  __syncthreads();

  conv_rows_f32<7, ROWS>(xt, wsm + W7OFF, tx, acc);

  float* __restrict__ oo = out + (size_t)s*NPIX + (size_t)by*HW + tx;
  #pragma unroll
  for (int r = 0; r < ROWS; ++r)
    oo[(size_t)r*HW] = acc[r];
}

// ===========================================================================
extern "C" void kernel_launch(void* const* d_in, const int* in_sizes, int n_in,
                              void* d_out, int out_size, void* d_ws, size_t ws_size,
                              hipStream_t stream)
{
  const float* x  = (const float*)d_in[0];
  const float* w3 = (const float*)d_in[1];
  const float* w5 = (const float*)d_in[2];
  const float* w7 = (const float*)d_in[3];
  float* out = (float*)d_out;
  char* ws = (char*)d_ws;

  const size_t SIMS_B = (size_t)NF*NSAMP*NPIX*sizeof(float);   // 192 MB
  const size_t CNT_B  = (size_t)NQ*CPAD*sizeof(unsigned);      // 24 KB each

  float*    sims = (float*)ws;
  unsigned* cntA = (unsigned*)(ws + SIMS_B);
  unsigned* cntC = cntA + (size_t)NQ*CPAD;
  unsigned* tlo  = cntC + (size_t)NQ*CPAD;
  unsigned* thi  = tlo + 8;
  unsigned* thb  = thi + 8;
  unsigned* cand = thb + NQ + NQ;      // spare NQ gap

  hipMemsetAsync(cntA, 0, 2*CNT_B, stream);   // cntA + cntC contiguous

  winit<<<1, 64, 0, stream>>>(w3, w5, w7, tlo, thi);
  dim3 b512(512, 1, 1);
  dim3 sg(HW/ROWS, NSAMP, 1);          // 32 x 64 strips
  fwd_all<<<sg, b512, 0, stream>>>(x, w3, w5, w7, sims, tlo, thi,
                                   cntA, cntC, cand);
  sel_final<<<NQ, 256, 0, stream>>>(cntA, cntC, cand, sims, thb);
  bwd_all<<<sg, b512, 0, stream>>>(sims, w3, w5, w7, thb, out);
}